// Round 7
// baseline (36.853 us; speedup 1.0000x reference)
//
#include <hip/hip_runtime.h>

#define T_LEN  512
#define K_LEN  64
#define NFILT  32
#define NBATCH 64
#define SQRT_LOG2E 1.2011224087864498f
#define LN2        0.6931471805599453f

// result[lane] = src[lane-1], lane0 -> 0 (DPP wave_shr:1, bound_ctrl=1)
static __device__ __forceinline__ float wave_shr1(float x) {
    int r = __builtin_amdgcn_update_dpp(0, __builtin_bit_cast(int, x),
                                        0x138, 0xF, 0xF, true);
    return __builtin_bit_cast(float, r);
}

template <int N>
static __device__ __forceinline__ float row_ror(float x) {
    int r = __builtin_amdgcn_update_dpp(0, __builtin_bit_cast(int, x),
                                        0x120 + N, 0xF, 0xF, true);
    return __builtin_bit_cast(float, r);
}

static __device__ __forceinline__ float exp2_fast(float x) {
#if __has_builtin(__builtin_amdgcn_exp2f)
    return __builtin_amdgcn_exp2f(x);
#else
    return exp2f(x);
#endif
}

// Linear-domain band-limited soft-DTW, ONE problem per wave, 2048 waves
// (2 waves/SIMD -- max TLP for this problem count; rounds 4-6 proved
// 1 wave/SIMD stalls at ~35% VALUBusy regardless of operand source).
// Z = 2^S2 * exp(-D);  Z[i,j] = exp(-C)*(Z[i-1,j] + Z[i,j-1] + Z[i-1,j-1]).
// x flows right one lane per step via DPP; x[d] injected at lane 0 from
// SGPR buffers. The w = exp2(-C) stream is software-pipelined 2 steps ahead
// of the prev-chain (rotating w0/w1) so exp latency never sits on the chain.
__global__ __launch_bounds__(256) void dtw_kernel(const float* __restrict__ x,
                                                  const float* __restrict__ protos,
                                                  float* __restrict__ out) {
    const int tid  = threadIdx.x;
    const int lane = tid & 63;
    const int wid  = tid >> 6;
    const int idx  = (blockIdx.x << 2) | wid;     // 0..2047
    const int b    = idx >> 5;
    const int f    = idx & 31;

    const float* __restrict__ xr = x + b * T_LEN;   // wave-uniform row
    const float pn = -protos[f * K_LEN + lane] * SQRT_LOG2E;
    const float jj = (float)lane / 63.0f;
    const bool lane0 = (lane == 0);

    // exact fp32 band interval per column (same predicate as reference)
    int a0 = 0, b0 = T_LEN - 1;
    while (a0 < b0) { int m = (a0 + b0) >> 1;
        if ((float)m / 511.0f - jj >= -0.2f) b0 = m; else a0 = m + 1; }
    const int ilo = a0;
    a0 = 0; b0 = T_LEN - 1;
    while (a0 < b0) { int m = (a0 + b0 + 1) >> 1;
        if ((float)m / 511.0f - jj <= 0.2f) a0 = m; else b0 = m - 1; }
    const int ihi = a0;

    const unsigned range = (unsigned)(ihi - ilo);
    unsigned t = (unsigned)(-(lane + ilo));   // mask counter, tracks LEAD pos
    float xv = 0.0f, prev = 0.0f;
    float dgp = lane0 ? 1.0f : 0.0f;          // Z[-1,-1] = 1
    int   S2  = 0;
    float w0, w1;                             // pipelined w slots (parity g&1)

#define LEAD_COMMON(W) do {                                     \
        float sel_ = (t <= range) ? 0.0f : -3.0e38f;            \
        ++t;                                                    \
        float ds_  = __builtin_fmaf(xv, SQRT_LOG2E, pn);        \
        W = exp2_fast(__builtin_fmaf(ds_, -ds_, sel_));         \
    } while (0)

#define LEAD_INJ(W, SV) do {                                    \
        float xs_ = wave_shr1(xv);                              \
        xv = lane0 ? (SV) : xs_;                                \
        LEAD_COMMON(W);                                         \
    } while (0)

#define LEAD_NOINJ(W) do {                                      \
        xv = wave_shr1(xv);    /* lane0 gets 0; masked anyway */ \
        LEAD_COMMON(W);                                         \
    } while (0)

#define CONSUME(W) do {                                         \
        float l_ = wave_shr1(prev);                             \
        float a_ = prev + dgp;                                  \
        dgp  = l_;                                              \
        prev = (a_ + l_) * (W);                                 \
    } while (0)

#define RENORM() do {                                                        \
        float m_ = prev;                                                     \
        m_ = fmaxf(m_, row_ror<8>(m_));                                      \
        m_ = fmaxf(m_, row_ror<4>(m_));                                      \
        m_ = fmaxf(m_, row_ror<2>(m_));                                      \
        m_ = fmaxf(m_, row_ror<1>(m_));                                      \
        int mi_ = __builtin_bit_cast(int, m_);                               \
        unsigned r0_ = (unsigned)__builtin_amdgcn_readlane(mi_, 0);          \
        unsigned r1_ = (unsigned)__builtin_amdgcn_readlane(mi_, 16);         \
        unsigned r2_ = (unsigned)__builtin_amdgcn_readlane(mi_, 32);         \
        unsigned r3_ = (unsigned)__builtin_amdgcn_readlane(mi_, 48);         \
        unsigned ra_ = r0_ > r1_ ? r0_ : r1_;                                \
        unsigned rb_ = r2_ > r3_ ? r2_ : r3_;                                \
        unsigned mx_ = ra_ > rb_ ? ra_ : rb_;                                \
        int e_  = (int)((mx_ >> 23) & 0xFF);                                 \
        int Me_ = 284 - e_;                                                  \
        Me_ = Me_ < 1 ? 1 : (Me_ > 254 ? 254 : Me_);                         \
        float M_ = __builtin_bit_cast(float, Me_ << 23);                     \
        S2  += Me_ - 127;                                                    \
        prev *= M_;                                                          \
        dgp  *= M_;                                                          \
    } while (0)

    // wave-uniform injection buffers (SGPRs), double-buffered per 32-chunk
    float SA[32], SB[32];
#pragma unroll
    for (int k = 0; k < 32; ++k) SA[k] = xr[k];          // chunk 0

    LEAD_INJ(w0, SA[0]);   // pipeline prologue: positions 0, 1
    LEAD_INJ(w1, SA[1]);

#pragma unroll 1
    for (int c = 0; c < 7; ++c) {                        // chunks m=0..13
        const int o1 = (2 * c + 1) * 32;
#pragma unroll
        for (int k = 0; k < 32; ++k) SB[k] = xr[o1 + k];
#pragma unroll
        for (int k = 0; k < 32; ++k) {                   // g = 64c + k
            float sv = (k <= 29) ? SA[k + 2] : SB[k - 30];
            if (k & 1) { CONSUME(w1); LEAD_INJ(w1, sv); }
            else       { CONSUME(w0); LEAD_INJ(w0, sv); }
        }
        RENORM();
        const int o2 = (2 * c + 2) * 32;
#pragma unroll
        for (int k = 0; k < 32; ++k) SA[k] = xr[o2 + k];
#pragma unroll
        for (int k = 0; k < 32; ++k) {                   // g = 64c + 32 + k
            float sv = (k <= 29) ? SB[k + 2] : SA[k - 30];
            if (k & 1) { CONSUME(w1); LEAD_INJ(w1, sv); }
            else       { CONSUME(w0); LEAD_INJ(w0, sv); }
        }
        RENORM();
    }
    // chunk 14 (g=448..479): cur=SA, prefetch chunk 15 into SB
#pragma unroll
    for (int k = 0; k < 32; ++k) SB[k] = xr[15 * 32 + k];
#pragma unroll
    for (int k = 0; k < 32; ++k) {
        float sv = (k <= 29) ? SA[k + 2] : SB[k - 30];
        if (k & 1) { CONSUME(w1); LEAD_INJ(w1, sv); }
        else       { CONSUME(w0); LEAD_INJ(w0, sv); }
    }
    RENORM();
    // chunk 15 (g=480..511): cur=SB; lead positions 512,513 have no x
#pragma unroll
    for (int k = 0; k < 32; ++k) {
        if (k & 1) { CONSUME(w1); if (k <= 29) LEAD_INJ(w1, SB[k + 2]); else LEAD_NOINJ(w1); }
        else       { CONSUME(w0); if (k <= 29) LEAD_INJ(w0, SB[k + 2]); else LEAD_NOINJ(w0); }
    }
    RENORM();
    // tail 1: g=512..543
#pragma unroll
    for (int k = 0; k < 32; ++k) {
        if (k & 1) { CONSUME(w1); LEAD_NOINJ(w1); }
        else       { CONSUME(w0); LEAD_NOINJ(w0); }
    }
    RENORM();
    // tail 2: g=544..572, then 573/574 consume-only (their w already computed)
#pragma unroll
    for (int k = 0; k < 29; ++k) {
        if (k & 1) { CONSUME(w1); LEAD_NOINJ(w1); }
        else       { CONSUME(w0); LEAD_NOINJ(w0); }
    }
    CONSUME(w1);   // g=573
    CONSUME(w0);   // g=574

    if (lane == 63) {
        float D = ((float)S2 - log2f(prev)) * LN2;
        out[b * NFILT + f] = D * (1.0f / (float)T_LEN);
    }
#undef LEAD_COMMON
#undef LEAD_INJ
#undef LEAD_NOINJ
#undef CONSUME
#undef RENORM
}

extern "C" void kernel_launch(void* const* d_in, const int* in_sizes, int n_in,
                              void* d_out, int out_size, void* d_ws, size_t ws_size,
                              hipStream_t stream) {
    const float* x      = (const float*)d_in[0];
    const float* protos = (const float*)d_in[1];
    float* out          = (float*)d_out;

    dim3 grid(512);    // 512 blocks x 4 waves = 2048 waves = 2 waves/SIMD
    dim3 block(256);   // one (b,f) problem per wave
    hipLaunchKernelGGL(dtw_kernel, grid, block, 0, stream, x, protos, out);
}

// Round 9
// 28.458 us; speedup vs baseline: 1.2950x; 1.2950x over previous
//
#include <hip/hip_runtime.h>

#define T_LEN  512
#define K_LEN  64
#define NFILT  32
#define NBATCH 64
#define XOFS   64                 // pad: min element index = XOFS-63 = 1
#define XS_SZ  640                // max element index read = 639
#define SQRT_LOG2E 1.2011224087864498f
#define LN2        0.6931471805599453f

// result[lane] = src[lane-1], lane0 -> 0 (DPP wave_shr:1, bound_ctrl=1)
static __device__ __forceinline__ float wave_shr1(float x) {
    int r = __builtin_amdgcn_update_dpp(0, __builtin_bit_cast(int, x),
                                        0x138, 0xF, 0xF, true);
    return __builtin_bit_cast(float, r);
}

template <int N>
static __device__ __forceinline__ float row_ror(float x) {
    int r = __builtin_amdgcn_update_dpp(0, __builtin_bit_cast(int, x),
                                        0x120 + N, 0xF, 0xF, true);
    return __builtin_bit_cast(float, r);
}

static __device__ __forceinline__ float exp2_fast(float x) {
#if __has_builtin(__builtin_amdgcn_exp2f)
    return __builtin_amdgcn_exp2f(x);
#else
    return exp2f(x);
#endif
}

// Linear-domain band-limited soft-DTW, 2 problems/wave (f, f+16; same b),
// 1024 waves. Z = 2^S2 * exp(-D);
// Z[i,j] = exp(-C[i,j]) * (Z[i-1,j] + Z[i,j-1] + Z[i-1,j-1]).
//
// PHASE-SPLIT: per 32-step chunk, a batch phase computes all 64 w=exp2(-C)
// values (independent -> issue-pipelined; band mask folded in as exact 0)
// and PINS them live via asm, so the serial core phase is 8 pure-VALU ops
// per step with no trans/memory latency on the recurrence chain.
//
// RENORM: every 32 steps, rescale so wave-max ~= 2^30 (proven R2-R7).
// Cadence/target are DECAY-limited, not growth-limited: w <= 1 and the max
// typically shrinks ~e^-1..e^-3 per step, so from 2^30 the floor stays above
// the 2^-126 flush over 32 steps. (R8's 2^10/64-step retune underflowed.)
__global__ __launch_bounds__(256) void dtw_kernel(const float* __restrict__ x,
                                                  const float* __restrict__ protos,
                                                  float* __restrict__ out) {
    __shared__ float xs[XS_SZ];
    const int tid  = threadIdx.x;
    const int lane = tid & 63;
    const int wid  = tid >> 6;
    const int b    = blockIdx.x >> 2;               // 256 blocks: 4 per b
    const int fA   = ((blockIdx.x & 3) << 2) | wid; // 0..15
    const int fB   = fA + 16;

    for (int t0i = tid; t0i < XS_SZ; t0i += 256) {
        int i = t0i - XOFS;
        xs[t0i] = (i >= 0 && i < T_LEN) ? x[b * T_LEN + i] * SQRT_LOG2E : 0.0f;
    }
    __syncthreads();

    const float pAn = -protos[fA * K_LEN + lane] * SQRT_LOG2E;
    const float pBn = -protos[fB * K_LEN + lane] * SQRT_LOG2E;
    const float jj  = (float)lane / 63.0f;

    // exact fp32 band interval per column (same predicate as reference)
    int a0 = 0, b0 = T_LEN - 1;
    while (a0 < b0) { int m = (a0 + b0) >> 1;
        if ((float)m / 511.0f - jj >= -0.2f) b0 = m; else a0 = m + 1; }
    const int ilo = a0;
    a0 = 0; b0 = T_LEN - 1;
    while (a0 < b0) { int m = (a0 + b0 + 1) >> 1;
        if ((float)m / 511.0f - jj <= 0.2f) a0 = m; else b0 = m - 1; }
    const int ihi = a0;

    const unsigned range = (unsigned)(ihi - ilo);
    unsigned t_chunk = (unsigned)(-(lane + ilo));   // t at current chunk start
    float prevA = 0.0f, prevB = 0.0f;
    float dgpA  = (lane == 0) ? 1.0f : 0.0f;        // Z[-1,-1] = 1
    float dgpB  = dgpA;
    int   S2A = 0, S2B = 0;
    const float* bptr = &xs[XOFS - lane];           // x source for chunk start

    float wA[32], wB[32];

    // batch: 32 ds_reads + 64 independent exps, each pinned live at this point
#define BATCH32() do {                                                       \
        float xv_[32];                                                       \
        _Pragma("unroll")                                                    \
        for (int k = 0; k < 32; ++k) xv_[k] = bptr[k];                       \
        _Pragma("unroll")                                                    \
        for (int k = 0; k < 32; ++k) {                                       \
            unsigned tk_ = t_chunk + (unsigned)k;                            \
            float sel_ = (tk_ <= range) ? 0.0f : -3.0e38f;                   \
            float dA_ = xv_[k] + pAn;                                        \
            float dB_ = xv_[k] + pBn;                                        \
            wA[k] = exp2_fast(__builtin_fmaf(dA_, -dA_, sel_));              \
            wB[k] = exp2_fast(__builtin_fmaf(dB_, -dB_, sel_));              \
            asm volatile("" : "+v"(wA[k]), "+v"(wB[k]));                     \
        }                                                                    \
        t_chunk += 32; bptr += 32;                                           \
    } while (0)

    // core: pure serial recurrence, 8 VALU/step, no trans/memory
#define CORE(N) do {                                                         \
        _Pragma("unroll")                                                    \
        for (int k = 0; k < (N); ++k) {                                      \
            float lA_ = wave_shr1(prevA);                                    \
            float lB_ = wave_shr1(prevB);                                    \
            float aA_ = prevA + dgpA;                                        \
            float aB_ = prevB + dgpB;                                        \
            dgpA = lA_; dgpB = lB_;                                          \
            prevA = (aA_ + lA_) * wA[k];                                     \
            prevB = (aB_ + lB_) * wB[k];                                     \
        }                                                                    \
    } while (0)

    // wave-uniform power-of-2 renorm to max ~ 2^30 (Me = 284 - e), cadence 32
#define RENORM_HALF(PV, DG, S2) do {                                         \
        float m_ = PV;                                                       \
        m_ = fmaxf(m_, row_ror<8>(m_));                                      \
        m_ = fmaxf(m_, row_ror<4>(m_));                                      \
        m_ = fmaxf(m_, row_ror<2>(m_));                                      \
        m_ = fmaxf(m_, row_ror<1>(m_));                                      \
        int mi_ = __builtin_bit_cast(int, m_);                               \
        unsigned r0_ = (unsigned)__builtin_amdgcn_readlane(mi_, 0);          \
        unsigned r1_ = (unsigned)__builtin_amdgcn_readlane(mi_, 16);         \
        unsigned r2_ = (unsigned)__builtin_amdgcn_readlane(mi_, 32);         \
        unsigned r3_ = (unsigned)__builtin_amdgcn_readlane(mi_, 48);         \
        unsigned ra_ = r0_ > r1_ ? r0_ : r1_;                                \
        unsigned rb_ = r2_ > r3_ ? r2_ : r3_;                                \
        unsigned mx_ = ra_ > rb_ ? ra_ : rb_;                                \
        int e_  = (int)((mx_ >> 23) & 0xFF);                                 \
        int Me_ = 284 - e_;                                                  \
        Me_ = Me_ < 1 ? 1 : (Me_ > 254 ? 254 : Me_);                         \
        float M_ = __builtin_bit_cast(float, Me_ << 23);                     \
        S2 += Me_ - 127;                                                     \
        PV *= M_;                                                            \
        DG *= M_;                                                            \
    } while (0)

#define RENORM() do { RENORM_HALF(prevA, dgpA, S2A);                         \
                      RENORM_HALF(prevB, dgpB, S2B); } while (0)

    // chunks 0..16 (full 32 steps each); renorm every chunk (proven cadence)
#pragma unroll 1
    for (int c = 0; c < 17; ++c) {
        BATCH32();
        CORE(32);
        RENORM();
    }
    // chunk 17: steps 544..574 (31 steps)
    BATCH32();
    CORE(31);

    if (lane == 63) {
        float DA = ((float)S2A - log2f(prevA)) * LN2;
        float DB = ((float)S2B - log2f(prevB)) * LN2;
        out[b * NFILT + fA] = DA * (1.0f / (float)T_LEN);
        out[b * NFILT + fB] = DB * (1.0f / (float)T_LEN);
    }
#undef BATCH32
#undef CORE
#undef RENORM_HALF
#undef RENORM
}

extern "C" void kernel_launch(void* const* d_in, const int* in_sizes, int n_in,
                              void* d_out, int out_size, void* d_ws, size_t ws_size,
                              hipStream_t stream) {
    const float* x      = (const float*)d_in[0];
    const float* protos = (const float*)d_in[1];
    float* out          = (float*)d_out;

    dim3 grid(NBATCH * 4);   // 256 blocks x 4 waves = 1024 waves (1/SIMD)
    dim3 block(256);         // each wave: 2 problems (f, f+16), same b
    hipLaunchKernelGGL(dtw_kernel, grid, block, 0, stream, x, protos, out);
}